// Round 9
// baseline (175.265 us; speedup 1.0000x reference)
//
#include <hip/hip_runtime.h>
#include <cstddef>
#include <cstdint>

// LocalAttention MI355X round 9: best-of composition.
//   cvt_all:   w_qkv, w_out, x fp32 -> bf16                    (round 5+)
//   gemm_qkv:  BK=64 MFMA core, XOR-swizzled global_load_lds   (round 7/8)
//   attn_f2:   round-6 attn_fused2 VERBATIM: 16x16 pixel tile, 20x20x64
//              halo (57.6 KB LDS), 2 fills / 4 barriers, 16-dim register
//              chunks, plain launch_bounds(256). Proven ~37 us, no spill.
//              (round-7/8 d-split regressed: 4 latency-bound fills with only
//              ~1600 VALU between barriers -> wave convoys. Fewer, bigger
//              stages with more compute per barrier win.)
//   gemm_out:  BK=64 core, fp32 out + bias.
// ws: 86 MB of 256 MiB.

namespace {

typedef short s16x8 __attribute__((ext_vector_type(8)));
typedef unsigned short u16x8 __attribute__((ext_vector_type(8)));
typedef float f32x4 __attribute__((ext_vector_type(4)));

constexpr int kHeads = 8;
constexpr int kN = 4096;          // pixels per image
constexpr float kScale = 0.125f;  // 64^-0.5

__device__ inline float b2f(unsigned short u) {
  return __uint_as_float((unsigned)u << 16);
}
__device__ inline unsigned short f2b(float x) {
  unsigned u = __float_as_uint(x);  // RNE
  return (unsigned short)((u + 0x7fffu + ((u >> 16) & 1u)) >> 16);
}

// async global->LDS, 16 B per lane; LDS dest = wave-uniform base + lane*16
__device__ __forceinline__ void g2l16(const unsigned short* g,
                                      unsigned short* l) {
  __builtin_amdgcn_global_load_lds(
      (const __attribute__((address_space(1))) void*)g,
      (__attribute__((address_space(3))) void*)l, 16, 0, 0);
}

// ---------------- fp32 -> bf16 for all three tensors -------------------------
__global__ __launch_bounds__(256) void cvt_all(
    const float* __restrict__ wq, const float* __restrict__ wo,
    const float* __restrict__ x, unsigned short* __restrict__ wqb,
    unsigned short* __restrict__ wob, unsigned short* __restrict__ xb) {
  const int i = blockIdx.x * 256 + threadIdx.x;  // 0..1179647
  const float* src;
  unsigned short* dst;
  int off;
  if (i < 98304) {
    src = wq; dst = wqb; off = i;
  } else if (i < 131072) {
    src = wo; dst = wob; off = i - 98304;
  } else {
    src = x; dst = xb; off = i - 131072;
  }
  const float4 a = ((const float4*)src)[off * 2];
  const float4 b = ((const float4*)src)[off * 2 + 1];
  u16x8 o;
  o[0] = f2b(a.x); o[1] = f2b(a.y); o[2] = f2b(a.z); o[3] = f2b(a.w);
  o[4] = f2b(b.x); o[5] = f2b(b.y); o[6] = f2b(b.z); o[7] = f2b(b.w);
  *(u16x8*)(dst + (size_t)off * 8) = o;
}

// ---------------- MFMA GEMM core: 128x128 tile, K=512, BK=64 ----------------
// XOR-swizzled staging: lane stages logical k-seg (lane&7)^(row&7) so the
// g2l16-forced layout (base + lane*16B) yields bank-spread ds_read_b128.
__device__ __forceinline__ void mfma_512(const unsigned short* __restrict__ A,
                                         const unsigned short* __restrict__ W,
                                         int m0, int n0, int tid,
                                         unsigned short* As, unsigned short* Bs,
                                         f32x4 (&acc)[4][4]) {
  const int lane = tid & 63;
  const int wv = tid >> 6;
  const int wm = wv & 1, wn = wv >> 1;
  const int rsub = lane >> 3;              // row within 8-row group
  const int slog = (lane & 7) ^ rsub;      // logical k-seg this lane stages
#pragma unroll
  for (int i = 0; i < 4; ++i)
#pragma unroll
    for (int j = 0; j < 4; ++j) acc[i][j] = f32x4{0.f, 0.f, 0.f, 0.f};

  for (int k0 = 0; k0 < 512; k0 += 64) {
#pragma unroll
    for (int it = 0; it < 4; ++it) {
      const int g = wv * 4 + it;  // 0..15 -> 8-row group
      const int row = g * 8 + rsub;
      g2l16(A + (size_t)(m0 + row) * 512 + k0 + slog * 8, As + g * 512);
      g2l16(W + (size_t)(n0 + row) * 512 + k0 + slog * 8, Bs + g * 512);
    }
    __syncthreads();
#pragma unroll
    for (int kh = 0; kh < 2; ++kh) {
      s16x8 af[4], bf[4];
      const int q = kh * 4 + (lane >> 4);  // logical k-seg wanted
#pragma unroll
      for (int i = 0; i < 4; ++i) {
        const int Ra = wm * 64 + i * 16 + (lane & 15);
        af[i] = *(const s16x8*)&As[Ra * 64 + ((q ^ (Ra & 7)) * 8)];
        const int Rb = wn * 64 + i * 16 + (lane & 15);
        bf[i] = *(const s16x8*)&Bs[Rb * 64 + ((q ^ (Rb & 7)) * 8)];
      }
#pragma unroll
      for (int i = 0; i < 4; ++i)
#pragma unroll
        for (int j = 0; j < 4; ++j)
          acc[i][j] = __builtin_amdgcn_mfma_f32_16x16x32_bf16(
              af[i], bf[j], acc[i][j], 0, 0, 0);
    }
    __syncthreads();
  }
}

// ---------------- QKV projection GEMM, full M=16384 --------------------------
__global__ __launch_bounds__(256, 3) void gemm_qkv(
    const unsigned short* __restrict__ A, const unsigned short* __restrict__ W,
    unsigned short* __restrict__ Qb, unsigned short* __restrict__ Kb,
    unsigned short* __restrict__ Vb) {
  __shared__ unsigned short As[8192], Bs[8192];  // 16 KB each
  const int tid = threadIdx.x;
  const int id = blockIdx.x;
  const int xcd = id & 7;
  const int j = id >> 3;            // 0..191
  const int by = xcd * 16 + j / 12; // 0..127
  const int bx = j % 12;
  f32x4 acc[4][4];
  mfma_512(A, W, by * 128, bx * 128, tid, As, Bs, acc);

  const int lane = tid & 63;
  const int wv = tid >> 6;
  const int wm = wv & 1, wn = wv >> 1;
  const int cn = bx * 128 + wn * 64;  // 64-aligned => head/qkv wave-uniform
  unsigned short* dst = (cn < 512) ? Qb : (cn < 1024 ? Kb : Vb);
  const int head = (cn >> 6) & 7;
  const int colb = lane & 15;
#pragma unroll
  for (int mi = 0; mi < 4; ++mi) {
#pragma unroll
    for (int r = 0; r < 4; ++r) {
      const int m = by * 128 + wm * 64 + mi * 16 + (lane >> 4) * 4 + r;
      const int b = m >> 12;
      const int p = m & 4095;
      unsigned short* o =
          dst + ((size_t)(b * kHeads + head) * kN + p) * 64 + colb;
#pragma unroll
      for (int ni = 0; ni < 4; ++ni) o[ni * 16] = f2b(acc[mi][ni][r]);
    }
  }
}

// ---------------- out-projection GEMM ----------------------------------------
__global__ __launch_bounds__(256, 3) void gemm_out(
    const unsigned short* __restrict__ A, const unsigned short* __restrict__ W,
    const float* __restrict__ bias, float* __restrict__ out) {
  __shared__ unsigned short As[8192], Bs[8192];
  const int tid = threadIdx.x;
  const int id = blockIdx.x;
  const int xcd = id & 7;
  const int j = id >> 3;               // 0..63
  const int by = xcd * 16 + (j >> 2);  // 0..127
  const int bx = j & 3;
  f32x4 acc[4][4];
  mfma_512(A, W, by * 128, bx * 128, tid, As, Bs, acc);

  const int lane = tid & 63;
  const int wv = tid >> 6;
  const int wm = wv & 1, wn = wv >> 1;
  float bvr[4];
#pragma unroll
  for (int ni = 0; ni < 4; ++ni)
    bvr[ni] = bias[bx * 128 + wn * 64 + ni * 16 + (lane & 15)];
#pragma unroll
  for (int mi = 0; mi < 4; ++mi) {
#pragma unroll
    for (int r = 0; r < 4; ++r) {
      const int m = by * 128 + wm * 64 + mi * 16 + (lane >> 4) * 4 + r;
      float* o = out + (size_t)m * 512 + bx * 128 + wn * 64 + (lane & 15);
#pragma unroll
      for (int ni = 0; ni < 4; ++ni) o[ni * 16] = acc[mi][ni][r] + bvr[ni];
    }
  }
}

// ---------------- fused local attention (round-6 proven version) -------------
// 16x16 pixel tile per block. One 57.6 KB LDS halo (20x20 rows x 64 dims,
// stride 72), used first for K (dots in 4x16-dim register chunks + softmax),
// then re-filled with V (o in 4x16-dim chunks, stored immediately).
// OOB halo rows zero => logit 0 participates in softmax (zero-pad semantics).
__global__ __launch_bounds__(256) void attn_f2(
    const unsigned short* __restrict__ Q, const unsigned short* __restrict__ K,
    const unsigned short* __restrict__ V, unsigned short* __restrict__ AO) {
  __shared__ unsigned short H[400 * 72];  // 57.6 KB -> 2 blocks/CU
  const int tid = threadIdx.x;
  const int bh = blockIdx.y;
  const int tile = blockIdx.x;
  const int ty0 = (tile >> 2) * 16, tx0 = (tile & 3) * 16;
  const size_t base = (size_t)bh * kN;
  const int pyl = tid >> 4, pxl = tid & 15;
  const int p = (ty0 + pyl) * 64 + tx0 + pxl;

  // ---- phase 1: K halo ----
  for (int i = tid; i < 3200; i += 256) {
    const int r = i >> 3, c = i & 7;
    const int gy = ty0 - 2 + r / 20;
    const int gx = tx0 - 2 + r % 20;
    u16x8 v = {};
    if ((unsigned)gy < 64u && (unsigned)gx < 64u)
      v = *(const u16x8*)(K + (base + gy * 64 + gx) * 64 + c * 8);
    *(u16x8*)&H[r * 72 + c * 8] = v;
  }
  __syncthreads();

  float dots[25];
#pragma unroll
  for (int f = 0; f < 25; ++f) dots[f] = 0.f;

  const unsigned short* qp = Q + (base + p) * 64;
#pragma unroll 1
  for (int c = 0; c < 4; ++c) {
    float qv[16];
    {
      const u16x8 a = *(const u16x8*)(qp + c * 16);
      const u16x8 b = *(const u16x8*)(qp + c * 16 + 8);
#pragma unroll
      for (int j = 0; j < 8; ++j) {
        qv[j] = b2f(a[j]);
        qv[8 + j] = b2f(b[j]);
      }
    }
#pragma unroll
    for (int fy = 0; fy < 5; ++fy) {
#pragma unroll
      for (int fx = 0; fx < 5; ++fx) {
        const unsigned short* kr =
            &H[((pyl + fy) * 20 + pxl + fx) * 72 + c * 16];
        const u16x8 a = *(const u16x8*)kr;
        const u16x8 b = *(const u16x8*)(kr + 8);
        float d = dots[fy * 5 + fx];
#pragma unroll
        for (int j = 0; j < 8; ++j) d = fmaf(qv[j], b2f(a[j]), d);
#pragma unroll
        for (int j = 0; j < 8; ++j) d = fmaf(qv[8 + j], b2f(b[j]), d);
        dots[fy * 5 + fx] = d;
      }
    }
  }

  // ---- softmax (registers only) ----
  float mx = -1e30f;
#pragma unroll
  for (int f = 0; f < 25; ++f) {
    dots[f] *= kScale;
    mx = fmaxf(mx, dots[f]);
  }
  float sum = 0.f;
#pragma unroll
  for (int f = 0; f < 25; ++f) {
    dots[f] = __expf(dots[f] - mx);
    sum += dots[f];
  }
  const float inv = 1.f / sum;
#pragma unroll
  for (int f = 0; f < 25; ++f) dots[f] *= inv;

  // ---- phase 2: V halo reuses H; o in 4 chunks of 16 dims ----
  __syncthreads();  // everyone done reading K halo
  for (int i = tid; i < 3200; i += 256) {
    const int r = i >> 3, c = i & 7;
    const int gy = ty0 - 2 + r / 20;
    const int gx = tx0 - 2 + r % 20;
    u16x8 v = {};
    if ((unsigned)gy < 64u && (unsigned)gx < 64u)
      v = *(const u16x8*)(V + (base + gy * 64 + gx) * 64 + c * 8);
    *(u16x8*)&H[r * 72 + c * 8] = v;
  }
  __syncthreads();

  const int b = bh >> 3, h = bh & 7;
  unsigned short* op = AO + ((size_t)(b * kN + p)) * 512 + h * 64;
#pragma unroll 1
  for (int c = 0; c < 4; ++c) {
    float o[16];
#pragma unroll
    for (int j = 0; j < 16; ++j) o[j] = 0.f;
#pragma unroll
    for (int fy = 0; fy < 5; ++fy) {
#pragma unroll
      for (int fx = 0; fx < 5; ++fx) {
        const unsigned short* vr =
            &H[((pyl + fy) * 20 + pxl + fx) * 72 + c * 16];
        const u16x8 a = *(const u16x8*)vr;
        const u16x8 b2 = *(const u16x8*)(vr + 8);
        const float wf = dots[fy * 5 + fx];
#pragma unroll
        for (int j = 0; j < 8; ++j) o[j] = fmaf(wf, b2f(a[j]), o[j]);
#pragma unroll
        for (int j = 0; j < 8; ++j) o[8 + j] = fmaf(wf, b2f(b2[j]), o[8 + j]);
      }
    }
    u16x8 pa, pb;
#pragma unroll
    for (int j = 0; j < 8; ++j) {
      pa[j] = f2b(o[j]);
      pb[j] = f2b(o[8 + j]);
    }
    *(u16x8*)(op + c * 16) = pa;
    *(u16x8*)(op + c * 16 + 8) = pb;
  }
}

}  // namespace

extern "C" void kernel_launch(void* const* d_in, const int* in_sizes, int n_in,
                              void* d_out, int out_size, void* d_ws,
                              size_t ws_size, hipStream_t stream) {
  (void)in_sizes; (void)n_in; (void)out_size; (void)ws_size;
  const float* x = (const float*)d_in[0];      // [4,4096,512]
  const float* w_qkv = (const float*)d_in[1];  // [1536,512]
  const float* w_out = (const float*)d_in[2];  // [512,512]
  const float* b_out = (const float*)d_in[3];  // [512]
  float* out = (float*)d_out;                  // [4,4096,512] fp32

  unsigned short* ws0 = (unsigned short*)d_ws;
  unsigned short* wqkvb = ws0;              //   786,432
  unsigned short* woutb = ws0 + 786432;     //   262,144
  unsigned short* xb = ws0 + 1048576;       // 8,388,608
  unsigned short* Qb = ws0 + 9437184;       // 8,388,608
  unsigned short* Kb = ws0 + 17825792;      // 8,388,608
  unsigned short* Vb = ws0 + 26214400;      // 8,388,608
  unsigned short* AO = ws0 + 34603008;      // 8,388,608 -> 86 MB total

  cvt_all<<<4608, 256, 0, stream>>>(w_qkv, w_out, x, wqkvb, woutb, xb);
  gemm_qkv<<<1536, 256, 0, stream>>>(xb, wqkvb, Qb, Kb, Vb);
  attn_f2<<<dim3(16, 32), 256, 0, stream>>>(Qb, Kb, Vb, AO);
  gemm_out<<<512, 256, 0, stream>>>(AO, woutb, b_out, out);
}

// Round 10
// 170.579 us; speedup vs baseline: 1.0275x; 1.0275x over previous
//
#include <hip/hip_runtime.h>
#include <cstddef>
#include <cstdint>

// LocalAttention MI355X round 10.
//   cvt_all:   w_qkv, w_out, x fp32 -> bf16
//   gemm_qkv:  BK=64 MFMA core, XOR-swizzled global_load_lds staging
//   attn_p2:   PAIR-SPLIT fused attention: 512-thread blocks, 16x16 pixel
//              tile, same 57.6 KB 20x20x64 halo + 2 fills/4 barriers as the
//              proven attn_f2, but thread pair (2t,2t+1) splits head_dim
//              32/32; dots combined with one intra-wave __shfl_xor(.,1).
//              Doubles waves/CU (8->16) at identical LDS/barrier structure
//              so VALU and LDS pipes overlap (r9: 41us ~= VALU 17.6 + LDS 16
//              serialized at 8 waves/CU lockstep).
//   gemm_out:  BK=64 core, fp32 out + bias.
// ws: 86 MB of 256 MiB.

namespace {

typedef short s16x8 __attribute__((ext_vector_type(8)));
typedef unsigned short u16x8 __attribute__((ext_vector_type(8)));
typedef float f32x4 __attribute__((ext_vector_type(4)));

constexpr int kHeads = 8;
constexpr int kN = 4096;          // pixels per image
constexpr float kScale = 0.125f;  // 64^-0.5

__device__ inline float b2f(unsigned short u) {
  return __uint_as_float((unsigned)u << 16);
}
__device__ inline unsigned short f2b(float x) {
  unsigned u = __float_as_uint(x);  // RNE
  return (unsigned short)((u + 0x7fffu + ((u >> 16) & 1u)) >> 16);
}

// async global->LDS, 16 B per lane; LDS dest = wave-uniform base + lane*16
__device__ __forceinline__ void g2l16(const unsigned short* g,
                                      unsigned short* l) {
  __builtin_amdgcn_global_load_lds(
      (const __attribute__((address_space(1))) void*)g,
      (__attribute__((address_space(3))) void*)l, 16, 0, 0);
}

// ---------------- fp32 -> bf16 for all three tensors -------------------------
__global__ __launch_bounds__(256) void cvt_all(
    const float* __restrict__ wq, const float* __restrict__ wo,
    const float* __restrict__ x, unsigned short* __restrict__ wqb,
    unsigned short* __restrict__ wob, unsigned short* __restrict__ xb) {
  const int i = blockIdx.x * 256 + threadIdx.x;  // 0..1179647
  const float* src;
  unsigned short* dst;
  int off;
  if (i < 98304) {
    src = wq; dst = wqb; off = i;
  } else if (i < 131072) {
    src = wo; dst = wob; off = i - 98304;
  } else {
    src = x; dst = xb; off = i - 131072;
  }
  const float4 a = ((const float4*)src)[off * 2];
  const float4 b = ((const float4*)src)[off * 2 + 1];
  u16x8 o;
  o[0] = f2b(a.x); o[1] = f2b(a.y); o[2] = f2b(a.z); o[3] = f2b(a.w);
  o[4] = f2b(b.x); o[5] = f2b(b.y); o[6] = f2b(b.z); o[7] = f2b(b.w);
  *(u16x8*)(dst + (size_t)off * 8) = o;
}

// ---------------- MFMA GEMM core: 128x128 tile, K=512, BK=64 ----------------
// XOR-swizzled staging: lane stages logical k-seg (lane&7)^(row&7) so the
// g2l16-forced layout (base + lane*16B) yields bank-spread ds_read_b128.
__device__ __forceinline__ void mfma_512(const unsigned short* __restrict__ A,
                                         const unsigned short* __restrict__ W,
                                         int m0, int n0, int tid,
                                         unsigned short* As, unsigned short* Bs,
                                         f32x4 (&acc)[4][4]) {
  const int lane = tid & 63;
  const int wv = tid >> 6;
  const int wm = wv & 1, wn = wv >> 1;
  const int rsub = lane >> 3;              // row within 8-row group
  const int slog = (lane & 7) ^ rsub;      // logical k-seg this lane stages
#pragma unroll
  for (int i = 0; i < 4; ++i)
#pragma unroll
    for (int j = 0; j < 4; ++j) acc[i][j] = f32x4{0.f, 0.f, 0.f, 0.f};

  for (int k0 = 0; k0 < 512; k0 += 64) {
#pragma unroll
    for (int it = 0; it < 4; ++it) {
      const int g = wv * 4 + it;  // 0..15 -> 8-row group
      const int row = g * 8 + rsub;
      g2l16(A + (size_t)(m0 + row) * 512 + k0 + slog * 8, As + g * 512);
      g2l16(W + (size_t)(n0 + row) * 512 + k0 + slog * 8, Bs + g * 512);
    }
    __syncthreads();
#pragma unroll
    for (int kh = 0; kh < 2; ++kh) {
      s16x8 af[4], bf[4];
      const int q = kh * 4 + (lane >> 4);  // logical k-seg wanted
#pragma unroll
      for (int i = 0; i < 4; ++i) {
        const int Ra = wm * 64 + i * 16 + (lane & 15);
        af[i] = *(const s16x8*)&As[Ra * 64 + ((q ^ (Ra & 7)) * 8)];
        const int Rb = wn * 64 + i * 16 + (lane & 15);
        bf[i] = *(const s16x8*)&Bs[Rb * 64 + ((q ^ (Rb & 7)) * 8)];
      }
#pragma unroll
      for (int i = 0; i < 4; ++i)
#pragma unroll
        for (int j = 0; j < 4; ++j)
          acc[i][j] = __builtin_amdgcn_mfma_f32_16x16x32_bf16(
              af[i], bf[j], acc[i][j], 0, 0, 0);
    }
    __syncthreads();
  }
}

// ---------------- QKV projection GEMM, full M=16384 --------------------------
__global__ __launch_bounds__(256, 3) void gemm_qkv(
    const unsigned short* __restrict__ A, const unsigned short* __restrict__ W,
    unsigned short* __restrict__ Qb, unsigned short* __restrict__ Kb,
    unsigned short* __restrict__ Vb) {
  __shared__ unsigned short As[8192], Bs[8192];  // 16 KB each
  const int tid = threadIdx.x;
  const int id = blockIdx.x;
  const int xcd = id & 7;
  const int j = id >> 3;            // 0..191
  const int by = xcd * 16 + j / 12; // 0..127
  const int bx = j % 12;
  f32x4 acc[4][4];
  mfma_512(A, W, by * 128, bx * 128, tid, As, Bs, acc);

  const int lane = tid & 63;
  const int wv = tid >> 6;
  const int wm = wv & 1, wn = wv >> 1;
  const int cn = bx * 128 + wn * 64;  // 64-aligned => head/qkv wave-uniform
  unsigned short* dst = (cn < 512) ? Qb : (cn < 1024 ? Kb : Vb);
  const int head = (cn >> 6) & 7;
  const int colb = lane & 15;
#pragma unroll
  for (int mi = 0; mi < 4; ++mi) {
#pragma unroll
    for (int r = 0; r < 4; ++r) {
      const int m = by * 128 + wm * 64 + mi * 16 + (lane >> 4) * 4 + r;
      const int b = m >> 12;
      const int p = m & 4095;
      unsigned short* o =
          dst + ((size_t)(b * kHeads + head) * kN + p) * 64 + colb;
#pragma unroll
      for (int ni = 0; ni < 4; ++ni) o[ni * 16] = f2b(acc[mi][ni][r]);
    }
  }
}

// ---------------- out-projection GEMM ----------------------------------------
__global__ __launch_bounds__(256, 3) void gemm_out(
    const unsigned short* __restrict__ A, const unsigned short* __restrict__ W,
    const float* __restrict__ bias, float* __restrict__ out) {
  __shared__ unsigned short As[8192], Bs[8192];
  const int tid = threadIdx.x;
  const int id = blockIdx.x;
  const int xcd = id & 7;
  const int j = id >> 3;               // 0..63
  const int by = xcd * 16 + (j >> 2);  // 0..127
  const int bx = j & 3;
  f32x4 acc[4][4];
  mfma_512(A, W, by * 128, bx * 128, tid, As, Bs, acc);

  const int lane = tid & 63;
  const int wv = tid >> 6;
  const int wm = wv & 1, wn = wv >> 1;
  float bvr[4];
#pragma unroll
  for (int ni = 0; ni < 4; ++ni)
    bvr[ni] = bias[bx * 128 + wn * 64 + ni * 16 + (lane & 15)];
#pragma unroll
  for (int mi = 0; mi < 4; ++mi) {
#pragma unroll
    for (int r = 0; r < 4; ++r) {
      const int m = by * 128 + wm * 64 + mi * 16 + (lane >> 4) * 4 + r;
      float* o = out + (size_t)m * 512 + bx * 128 + wn * 64 + (lane & 15);
#pragma unroll
      for (int ni = 0; ni < 4; ++ni) o[ni * 16] = acc[mi][ni][r] + bvr[ni];
    }
  }
}

// ---------------- fused local attention, pair-split --------------------------
// 512 threads/block, 16x16 pixel tile. Thread pair (2t,2t+1) = pixel t,
// halves the head_dim (32 dims each). Halo identical to attn_f2: 20x20 rows
// x 64 dims bf16 stride 72 (57.6 KB). K phase: partial dots over own 32 dims
// -> __shfl_xor(.,1) combine (pair is intra-wave). Softmax computed (redundantly)
// by both pair members. V phase: o over own 32 dims, disjoint stores.
// OOB halo rows zero => logit 0 participates in softmax (zero-pad semantics).
__global__ __launch_bounds__(512) void attn_p2(
    const unsigned short* __restrict__ Q, const unsigned short* __restrict__ K,
    const unsigned short* __restrict__ V, unsigned short* __restrict__ AO) {
  __shared__ unsigned short H[400 * 72];  // 57.6 KB -> 2 blocks/CU
  const int tid = threadIdx.x;            // 0..511
  const int bh = blockIdx.y;
  const int tile = blockIdx.x;
  const int ty0 = (tile >> 2) * 16, tx0 = (tile & 3) * 16;
  const size_t base = (size_t)bh * kN;
  const int pix = tid >> 1;   // 0..255
  const int dh = tid & 1;     // which 32-dim half
  const int pyl = pix >> 4, pxl = pix & 15;
  const int p = (ty0 + pyl) * 64 + tx0 + pxl;

  // ---- phase 1: K halo ----
  for (int i = tid; i < 3200; i += 512) {
    const int r = i >> 3, c = i & 7;
    const int gy = ty0 - 2 + r / 20;
    const int gx = tx0 - 2 + r % 20;
    u16x8 v = {};
    if ((unsigned)gy < 64u && (unsigned)gx < 64u)
      v = *(const u16x8*)(K + (base + gy * 64 + gx) * 64 + c * 8);
    *(u16x8*)&H[r * 72 + c * 8] = v;
  }
  __syncthreads();

  float dots[25];
#pragma unroll
  for (int f = 0; f < 25; ++f) dots[f] = 0.f;

  const unsigned short* qp = Q + (base + p) * 64 + dh * 32;
#pragma unroll 1
  for (int c = 0; c < 2; ++c) {  // two 16-dim chunks of this thread's half
    float qv[16];
    {
      const u16x8 a = *(const u16x8*)(qp + c * 16);
      const u16x8 b = *(const u16x8*)(qp + c * 16 + 8);
#pragma unroll
      for (int j = 0; j < 8; ++j) {
        qv[j] = b2f(a[j]);
        qv[8 + j] = b2f(b[j]);
      }
    }
#pragma unroll
    for (int fy = 0; fy < 5; ++fy) {
#pragma unroll
      for (int fx = 0; fx < 5; ++fx) {
        const unsigned short* kr =
            &H[((pyl + fy) * 20 + pxl + fx) * 72 + dh * 32 + c * 16];
        const u16x8 a = *(const u16x8*)kr;
        const u16x8 b = *(const u16x8*)(kr + 8);
        float d = dots[fy * 5 + fx];
#pragma unroll
        for (int j = 0; j < 8; ++j) d = fmaf(qv[j], b2f(a[j]), d);
#pragma unroll
        for (int j = 0; j < 8; ++j) d = fmaf(qv[8 + j], b2f(b[j]), d);
        dots[fy * 5 + fx] = d;
      }
    }
  }

  // ---- pair combine: lanes 2t,2t+1 are intra-wave ----
#pragma unroll
  for (int f = 0; f < 25; ++f) dots[f] += __shfl_xor(dots[f], 1, 64);

  // ---- softmax (registers only; both pair members compute identically) ----
  float mx = -1e30f;
#pragma unroll
  for (int f = 0; f < 25; ++f) {
    dots[f] *= kScale;
    mx = fmaxf(mx, dots[f]);
  }
  float sum = 0.f;
#pragma unroll
  for (int f = 0; f < 25; ++f) {
    dots[f] = __expf(dots[f] - mx);
    sum += dots[f];
  }
  const float inv = 1.f / sum;
#pragma unroll
  for (int f = 0; f < 25; ++f) dots[f] *= inv;

  // ---- phase 2: V halo reuses H ----
  __syncthreads();  // everyone done reading K halo
  for (int i = tid; i < 3200; i += 512) {
    const int r = i >> 3, c = i & 7;
    const int gy = ty0 - 2 + r / 20;
    const int gx = tx0 - 2 + r % 20;
    u16x8 v = {};
    if ((unsigned)gy < 64u && (unsigned)gx < 64u)
      v = *(const u16x8*)(V + (base + gy * 64 + gx) * 64 + c * 8);
    *(u16x8*)&H[r * 72 + c * 8] = v;
  }
  __syncthreads();

  const int b = bh >> 3, h = bh & 7;
  unsigned short* op = AO + ((size_t)(b * kN + p)) * 512 + h * 64 + dh * 32;
#pragma unroll 1
  for (int c = 0; c < 2; ++c) {
    float o[16];
#pragma unroll
    for (int j = 0; j < 16; ++j) o[j] = 0.f;
#pragma unroll
    for (int fy = 0; fy < 5; ++fy) {
#pragma unroll
      for (int fx = 0; fx < 5; ++fx) {
        const unsigned short* vr =
            &H[((pyl + fy) * 20 + pxl + fx) * 72 + dh * 32 + c * 16];
        const u16x8 a = *(const u16x8*)vr;
        const u16x8 b2 = *(const u16x8*)(vr + 8);
        const float wf = dots[fy * 5 + fx];
#pragma unroll
        for (int j = 0; j < 8; ++j) o[j] = fmaf(wf, b2f(a[j]), o[j]);
#pragma unroll
        for (int j = 0; j < 8; ++j) o[8 + j] = fmaf(wf, b2f(b2[j]), o[8 + j]);
      }
    }
    u16x8 pa, pb;
#pragma unroll
    for (int j = 0; j < 8; ++j) {
      pa[j] = f2b(o[j]);
      pb[j] = f2b(o[8 + j]);
    }
    *(u16x8*)(op + c * 16) = pa;
    *(u16x8*)(op + c * 16 + 8) = pb;
  }
}

}  // namespace

extern "C" void kernel_launch(void* const* d_in, const int* in_sizes, int n_in,
                              void* d_out, int out_size, void* d_ws,
                              size_t ws_size, hipStream_t stream) {
  (void)in_sizes; (void)n_in; (void)out_size; (void)ws_size;
  const float* x = (const float*)d_in[0];      // [4,4096,512]
  const float* w_qkv = (const float*)d_in[1];  // [1536,512]
  const float* w_out = (const float*)d_in[2];  // [512,512]
  const float* b_out = (const float*)d_in[3];  // [512]
  float* out = (float*)d_out;                  // [4,4096,512] fp32

  unsigned short* ws0 = (unsigned short*)d_ws;
  unsigned short* wqkvb = ws0;              //   786,432
  unsigned short* woutb = ws0 + 786432;     //   262,144
  unsigned short* xb = ws0 + 1048576;       // 8,388,608
  unsigned short* Qb = ws0 + 9437184;       // 8,388,608
  unsigned short* Kb = ws0 + 17825792;      // 8,388,608
  unsigned short* Vb = ws0 + 26214400;      // 8,388,608
  unsigned short* AO = ws0 + 34603008;      // 8,388,608 -> 86 MB total

  cvt_all<<<4608, 256, 0, stream>>>(w_qkv, w_out, x, wqkvb, woutb, xb);
  gemm_qkv<<<1536, 256, 0, stream>>>(xb, wqkvb, Qb, Kb, Vb);
  attn_p2<<<dim3(16, 32), 512, 0, stream>>>(Qb, Kb, Vb, AO);
  gemm_out<<<512, 256, 0, stream>>>(AO, woutb, b_out, out);
}